// Round 7
// baseline (44228.940 us; speedup 1.0000x reference)
//
#include <hip/hip_runtime.h>
#include <math.h>

#define NBLK    32          // worker blocks, all on ONE XCD (its 32 CUs)
#define NLAUNCH 256         // launched blocks; non-elected exit immediately
#define BS      512
#define NSTATE  17
#define NH      256
#define NX      273         // NH + NSTATE
#define WID     1024
#define NT      64
#define NSUB    8
#define ROWS_H  (WID/NBLK)  // 32 rows/block for 1024-wide layers
#define ROWS_L  (NH/NBLK)   // 8 rows/block for the 256-wide output layer
#define POLL_CAP 2000000    // fail fast instead of hanging

typedef unsigned long long u64;
typedef unsigned int u32;

__device__ __forceinline__ float softplus_f(float v) {
    return fmaxf(v, 0.f) + log1pf(expf(-fabsf(v)));
}

// ---- flag-gated single-sweep ATOMIC exchange (same-XCD L2) ----------------
// R6 lessons: (a) plain-store + buffer_inv data path is latently racy
// (absmax drifted with bit-identical math); only all-atomic transport
// reproduces 1.22e-4 exactly (R1/R5). (b) One shared flag line = hot-line
// serialization -> 22..63ms variance. New scheme, all through L2 atomic
// units (never stale, R5-proven):
//   producer: pack 32 row-values (LDS) -> 16x atomic_swap_x2 (pairs) ->
//             wave0 vmcnt(0) -> ONE 4B arrival swap arr[blk]=R (own line).
//   consumer: wave0 reads the 32 arrival slots (1 RMW each, separate
//             lines, pipelined), __all(v>=R); then ONE x2 add0-sweep
//             (512 RMW/block) gated by the flags -- no retry sweeps.
// Monotone R per slot: no rotation, no resets, no cross-launch aliasing
// (memset zeroes arr; atomics always read the true L2 state).
#define ARR_STRIDE 16   // u32s -> 64B: one arrival slot per cacheline

__device__ __forceinline__ void swap_x2(u64* p, u64 w) {
    asm volatile("global_atomic_swap_x2 %0, %1, off" :: "v"(p), "v"(w) : "memory");
}
__device__ __forceinline__ u64 add0_x2(const u64* p) {
    u64 w;
    asm volatile("global_atomic_add_x2 %0, %1, %2, off sc0\n\t"
                 "s_waitcnt vmcnt(0)"
                 : "=&v"(w) : "v"(p), "v"(0ULL) : "memory");
    return w;
}
__device__ __forceinline__ void arr_set(u32* arr, int blk, u32 Rv) {
    u32* p = arr + blk * ARR_STRIDE;
    asm volatile("global_atomic_swap %0, %1, off" :: "v"(p), "v"(Rv) : "memory");
}
__device__ __forceinline__ u32 arr_get(u32* arr, int idx) {
    u32* p = arr + idx * ARR_STRIDE;
    u32 v;
    asm volatile("global_atomic_add %0, %1, %2, off sc0\n\t"
                 "s_waitcnt vmcnt(0)"
                 : "=&v"(v) : "v"(p), "v"(0u) : "memory");
    return v;
}

// all 512 threads call; val is meaningful on laneH==0 (owner of rowH)
__device__ __forceinline__ void publish32(u64* z64, u32* arr, unsigned R,
                                          float* pair_s, int t, int blk,
                                          int rowH, int laneH, float val) {
    if (laneH == 0) pair_s[rowH] = val;
    __syncthreads();
    if (t < 16) {
        u64 w = ((u64)__float_as_uint(pair_s[2 * t + 1]) << 32)
              |  (u64)__float_as_uint(pair_s[2 * t]);
        swap_x2(z64 + blk * 16 + t, w);
    }
    if (t < 64) asm volatile("s_waitcnt vmcnt(0)" ::: "memory");
    if (t == 0) arr_set(arr, blk, R);
}
__device__ __forceinline__ void publish8(u64* dh64, u32* arr, unsigned R,
                                         float* pair_s, int t, int blk,
                                         int rowL, int laneL, float val) {
    if (laneL == 0) pair_s[rowL] = val;
    __syncthreads();
    if (t < 4) {
        u64 w = ((u64)__float_as_uint(pair_s[2 * t + 1]) << 32)
              |  (u64)__float_as_uint(pair_s[2 * t]);
        swap_x2(dh64 + blk * 4 + t, w);
    }
    if (t < 64) asm volatile("s_waitcnt vmcnt(0)" ::: "memory");
    if (t == 0) arr_set(arr, blk, R);
}
__device__ __forceinline__ void wait_all(u32* arr, unsigned R, int t) {
    if (t < 64) {
        const int idx = t & 31;
        int it = 0;
        for (;;) {
            u32 v = arr_get(arr, idx);
            if (__all((int)(v >= R))) break;
            if (++it > POLL_CAP) break;
        }
    }
    __syncthreads();
}
// wait + single-sweep gather of 1024 floats into LDS (thread t owns pair t)
__device__ __forceinline__ void consume_z(const u64* z64, u32* arr, unsigned R,
                                          float* z_s, int t) {
    wait_all(arr, R, t);
    u64 w = add0_x2(z64 + t);
    z_s[2 * t]     = __uint_as_float((u32)w);
    z_s[2 * t + 1] = __uint_as_float((u32)(w >> 32));
    __syncthreads();
}

extern "C" __global__ __launch_bounds__(BS, 2) void ode_kernel(
    const float* __restrict__ ts,   const float* __restrict__ W0,
    const float* __restrict__ b0,   const float* __restrict__ Wh,
    const float* __restrict__ bh,   const float* __restrict__ Wl,
    const float* __restrict__ bl,   const float* __restrict__ betaW,
    const float* __restrict__ betab,const float* __restrict__ hvec,
    const float* __restrict__ scale,const float* __restrict__ y0log,
    float* __restrict__ out, u64* zA64, u64* zB64, u64* dh64,
    u32* arr, unsigned* ctrl)
{
    const int t = threadIdx.x;

    __shared__ int   role_sh;
    __shared__ float y_s[NX];
    __shared__ float yn_s[NX];
    __shared__ float xm[NX];     // MLP-ordered input: [h(256), state(17)]
    __shared__ float k_s[NX];
    __shared__ float z_s[WID];
    __shared__ float red[8];
    __shared__ float pair_s[ROWS_H];
    __shared__ float dt_sh;
    extern __shared__ float wh2[];   // dynamic: 32 rows x 1024 of layer-3 (128 KB)

    // ---- XCD election (MALL atomics, one-time): first XCD with NBLK blocks
    // wins. 256 blocks, ~137KB LDS -> 1 block/CU, all co-resident.
    if (t == 0) {
        int xcd;
        asm volatile("s_getreg_b32 %0, hwreg(HW_REG_XCC_ID)" : "=s"(xcd));
        xcd &= 7;
        unsigned rk = atomicAdd(&ctrl[xcd], 1u);
        if (rk == NBLK - 1) atomicCAS(&ctrl[8], 0u, (unsigned)(xcd + 1));
        unsigned w; int it = 0;
        do {
            w = __hip_atomic_load(&ctrl[8], __ATOMIC_RELAXED, __HIP_MEMORY_SCOPE_AGENT);
        } while (w == 0u && ++it < POLL_CAP);
        role_sh = (w != 0u && xcd == (int)w - 1 && rk < NBLK) ? (int)rk : -1;
    }
    __syncthreads();
    const int blk = role_sh;
    if (blk < 0) return;

    const float scale0 = scale[0];
    const float betab0 = betab[0];
    unsigned R = 0;   // exchange round; identical sequence on all workers

    const int rowH = t >> 4, laneH = t & 15;
    const int growH = blk * ROWS_H + rowH;
    const int rowL = t >> 6, laneL = t & 63;
    const int growL = blk * ROWS_L + rowL;

    // ---- loop-invariant scalars ----
    const float b0r = b0[growH];
    float bhr[3];
    bhr[0] = bh[growH]; bhr[1] = bh[WID + growH]; bhr[2] = bh[2 * WID + growH];
    const float blr    = bl[growL];
    const float betaWr = (t < NH) ? betaW[t] : 0.f;
    const float* wlp = Wl + (size_t)growL * WID + laneL * 4;

    // ---- weight residency: h1,h2 in VGPRs (128), h3 slice in LDS (128KB),
    //      W0 in 18 regs, Wl streamed per stage (L2-resident).
    float4 wv0[16], wv1[16];
    {
        const float* whp = Wh + (size_t)growH * WID + laneH * 4;
        #pragma unroll
        for (int i = 0; i < 16; i++) wv0[i] = *(const float4*)(whp + i * 64);
        #pragma unroll
        for (int i = 0; i < 16; i++) wv1[i] = *(const float4*)(whp + WID * WID + i * 64);
    }
    {   // copy layer-3 row slice into LDS (coalesced float4)
        const float* src = Wh + 2 * (size_t)WID * WID + (size_t)blk * ROWS_H * WID;
        for (int i = t * 4; i < ROWS_H * WID; i += BS * 4)
            *(float4*)&wh2[i] = *(const float4*)&src[i];
    }
    float w0r[18];
    {
        const float* w0p = W0 + (size_t)growH * NX;
        #pragma unroll
        for (int i = 0; i < 18; i++) {
            int c = laneH + i * 16;
            w0r[i] = (c < NX) ? w0p[c] : 0.f;
        }
    }

    // ---- y0 = [softmax(y0_log), hvec] ----
    if (t < NSTATE) {
        float m = -1e30f;
        for (int j = 0; j < NSTATE; j++) m = fmaxf(m, y0log[j]);
        float ssum = 0.f;
        for (int j = 0; j < NSTATE; j++) ssum += expf(y0log[j] - m);
        y_s[t] = expf(y0log[t] - m) / ssum;
    }
    if (t < NH) y_s[NSTATE + t] = hvec[t];
    __syncthreads();

    if (blk == 0) {
        if (t < NSTATE) out[t] = y_s[t];
        if (t < NH)     out[NT * NSTATE + t] = y_s[NSTATE + t];
    }

    const float c_xi = 13.f / 12.f, c_mu = 0.041f / 12.f, c_sig = 91.f / 12.f,
                c_nu = 36.f / 12.f, c_gam = 1.8f / 12.f;

    for (int iv = 0; iv < NT - 1; iv++) {
        if (t == 0) dt_sh = (ts[iv + 1] - ts[iv]) * (1.f / NSUB);
        __syncthreads();
        const float dt = dt_sh;

        for (int sub = 0; sub < NSUB; sub++) {
            if (t < NX) yn_s[t] = y_s[t];

            for (int s = 0; s < 4; s++) {
                const float a   = (s == 0) ? 0.f : ((s == 3) ? 1.f : 0.5f);
                const float wgt = ((s == 0) || (s == 3)) ? dt * (1.f / 6.f) : dt * (1.f / 3.f);
                const float adt = a * dt;

                // ---- stage input, built directly in MLP order [h, state] ----
                if (t < NX) {
                    const int src = (t < NH) ? (NSTATE + t) : (t - NH);
                    float v = y_s[src];
                    if (s != 0) v = fmaf(adt, k_s[src], v);
                    xm[t] = v;
                }
                __syncthreads();

                // ---- L0: 1024x273, weights in regs (fmaf-pinned) ----
                {
                    float acc = 0.f;
                    #pragma unroll
                    for (int i = 0; i < 18; i++) {
                        int c = laneH + i * 16;
                        if (c < NX) acc = fmaf(w0r[i], xm[c], acc);
                    }
                    #pragma unroll
                    for (int m = 1; m < 16; m <<= 1) acc += __shfl_xor(acc, m, 16);
                    ++R;
                    publish32(zA64, arr, R, pair_s, t, blk, rowH, laneH,
                              softplus_f(acc + b0r));
                }

                // ---- beta head + dstate: overlaps other blocks' publishes ----
                {
                    if (t < NH) {
                        float p = betaWr * xm[t];
                        #pragma unroll
                        for (int m = 1; m < 64; m <<= 1) p += __shfl_xor(p, m, 64);
                        if ((t & 63) == 0) red[t >> 6] = p;
                    }
                    __syncthreads();
                    if (t == 0) {
                        const float* xs = xm + NH;
                        float sd  = red[0] + red[1] + red[2] + red[3] + betab0;
                        float bb1 = 8.f / (1.f + expf(-sd)) + 25.f;
                        float bb2 = 0.5f * bb1, bb3 = 0.35f * bb1, bb4 = 0.25f * bb1;
                        float M  = xs[0],  S1 = xs[1],  E1 = xs[2],  E2 = xs[3];
                        float E3 = xs[4],  E4 = xs[5],  I1 = xs[6],  I2 = xs[7];
                        float I3 = xs[8],  I4 = xs[9],  R1 = xs[10], R2 = xs[11];
                        float R3 = xs[12], R4 = xs[13], S2 = xs[14], S3 = xs[15];
                        float S4 = xs[16];
                        float I = I1 + I2 + I3 + I4, Rs = R1 + R2 + R3 + R4;
                        k_s[0]  = Rs * c_mu - (c_xi + c_mu) * M;
                        k_s[1]  = c_mu * (1.f - Rs) + c_xi * M - c_mu * S1 - bb1 * I * S1;
                        k_s[2]  = bb1 * I * S1 - (c_mu + c_sig) * E1;
                        k_s[3]  = bb2 * I * S2 - (c_mu + c_sig) * E2;
                        k_s[4]  = bb3 * I * S3 - (c_mu + c_sig) * E3;
                        k_s[5]  = bb4 * I * S4 - (c_mu + c_sig) * E4;
                        k_s[6]  = c_sig * E1 - (c_nu + c_mu) * I1;
                        k_s[7]  = c_sig * E2 - (c_nu + c_mu) * I2;
                        k_s[8]  = c_sig * E3 - (c_nu + c_mu) * I3;
                        k_s[9]  = c_sig * E4 - (c_nu + c_mu) * I4;
                        k_s[10] = c_nu * I1 - (c_mu + c_gam) * R1;
                        k_s[11] = c_nu * I2 - (c_mu + c_gam) * R2;
                        k_s[12] = c_nu * I3 - (c_mu + c_gam) * R3;
                        k_s[13] = c_nu * I4 - (c_mu + c_gam) * R4;
                        k_s[14] = c_gam * R1 - c_mu * S2 - bb2 * I * S2;
                        k_s[15] = c_gam * R2 - c_mu * S3 - bb3 * I * S3;
                        k_s[16] = c_gam * (R3 + R4) - c_mu * S4 - bb4 * I * S4;
                    }
                    // k_s[0..16] next read only after later wait_all barriers.
                }

                // ---- h1, h2: weights in registers (fmaf-pinned) ----
                auto hidden = [&](const float4 (&wv)[16], const u64* zin64,
                                  u64* zout64, float bias) {
                    consume_z(zin64, arr, R, z_s, t);
                    float acc = 0.f;
                    #pragma unroll
                    for (int i = 0; i < 16; i++) {
                        float4 zv = *(const float4*)(z_s + (laneH * 4 + i * 64));
                        acc = fmaf(wv[i].x, zv.x, acc);
                        acc = fmaf(wv[i].y, zv.y, acc);
                        acc = fmaf(wv[i].z, zv.z, acc);
                        acc = fmaf(wv[i].w, zv.w, acc);
                    }
                    #pragma unroll
                    for (int m = 1; m < 16; m <<= 1) acc += __shfl_xor(acc, m, 16);
                    ++R;
                    publish32(zout64, arr, R, pair_s, t, blk, rowH, laneH,
                              softplus_f(acc + bias));
                };

                hidden(wv0, zA64, zB64, bhr[0]);
                hidden(wv1, zB64, zA64, bhr[1]);

                // prefetch Wl row slice (L2-resident); overlaps h3 exchange
                float4 wvL[4];
                #pragma unroll
                for (int i = 0; i < 4; i++) wvL[i] = *(const float4*)(wlp + i * 256);

                // ---- h3: weights from LDS (fmaf-pinned) ----
                {
                    consume_z(zA64, arr, R, z_s, t);
                    const float* wr = wh2 + rowH * WID + laneH * 4;
                    float acc = 0.f;
                    #pragma unroll
                    for (int i = 0; i < 16; i++) {
                        float4 wv4 = *(const float4*)(wr + i * 64);
                        float4 zv  = *(const float4*)(z_s + (laneH * 4 + i * 64));
                        acc = fmaf(wv4.x, zv.x, acc);
                        acc = fmaf(wv4.y, zv.y, acc);
                        acc = fmaf(wv4.z, zv.z, acc);
                        acc = fmaf(wv4.w, zv.w, acc);
                    }
                    #pragma unroll
                    for (int m = 1; m < 16; m <<= 1) acc += __shfl_xor(acc, m, 16);
                    ++R;
                    publish32(zB64, arr, R, pair_s, t, blk, rowH, laneH,
                              softplus_f(acc + bhr[2]));
                }

                // ---- Wl: 256x1024, 8 rows/block; tanh epilogue ----
                {
                    consume_z(zB64, arr, R, z_s, t);
                    float acc = 0.f;
                    #pragma unroll
                    for (int i = 0; i < 4; i++) {
                        float4 zv = *(const float4*)(z_s + (laneL * 4 + i * 256));
                        acc = fmaf(wvL[i].x, zv.x, acc);
                        acc = fmaf(wvL[i].y, zv.y, acc);
                        acc = fmaf(wvL[i].z, zv.z, acc);
                        acc = fmaf(wvL[i].w, zv.w, acc);
                    }
                    #pragma unroll
                    for (int m = 1; m < 64; m <<= 1) acc += __shfl_xor(acc, m, 64);
                    ++R;
                    publish8(dh64, arr, R, pair_s, t, blk, rowL, laneL,
                             scale0 * tanhf(0.01f * (acc + blr)));
                }

                // ---- gather dh: flag-gated single sweep (128 x2 words) ----
                {
                    wait_all(arr, R, t);
                    if (t < 128) {
                        u64 w = add0_x2(dh64 + t);
                        k_s[NSTATE + 2 * t]     = __uint_as_float((u32)w);
                        k_s[NSTATE + 2 * t + 1] = __uint_as_float((u32)(w >> 32));
                    }
                    __syncthreads();
                    if (t < NX) yn_s[t] = fmaf(wgt, k_s[t], yn_s[t]);
                }
            } // stages

            __syncthreads();
            if (t < NX) y_s[t] = yn_s[t];
            __syncthreads();
        } // substeps

        if (blk == 0) {
            if (t < NSTATE) out[(iv + 1) * NSTATE + t] = y_s[t];
            if (t < NH)     out[NT * NSTATE + (iv + 1) * NH + t] = y_s[NSTATE + t];
        }
    } // intervals
}

extern "C" void kernel_launch(void* const* d_in, const int* in_sizes, int n_in,
                              void* d_out, int out_size, void* d_ws, size_t ws_size,
                              hipStream_t stream) {
    const float* ts    = (const float*)d_in[0];
    const float* W0    = (const float*)d_in[1];
    const float* b0    = (const float*)d_in[2];
    const float* Wh    = (const float*)d_in[3];
    const float* bh    = (const float*)d_in[4];
    const float* Wl    = (const float*)d_in[5];
    const float* bl    = (const float*)d_in[6];
    const float* betaW = (const float*)d_in[7];
    const float* betab = (const float*)d_in[8];
    const float* hvec  = (const float*)d_in[9];
    const float* scale = (const float*)d_in[10];
    const float* y0log = (const float*)d_in[11];
    float* out = (float*)d_out;

    u64*      zA64 = (u64*)d_ws;                          // 512*8 = 4 KB
    u64*      zB64 = (u64*)((char*)d_ws + 4096);          // 4 KB
    u64*      dh64 = (u64*)((char*)d_ws + 8192);          // 128*8 = 1 KB
    u32*      arr  = (u32*)((char*)d_ws + 9216);          // 32 x 64B = 2 KB
    unsigned* ctrl = (unsigned*)((char*)d_ws + 11264);    // cnt[8], winner

    // allow 128KB dynamic LDS (h3 weight slice)
    static int lds_set = 0;
    if (!lds_set) {
        hipFuncSetAttribute((const void*)ode_kernel,
                            hipFuncAttributeMaxDynamicSharedMemorySize, 131072);
        lds_set = 1;
    }

    // zero exchange buffers + arrival slots + election state
    hipMemsetAsync(d_ws, 0, 11328, stream);
    hipLaunchKernelGGL(ode_kernel, dim3(NLAUNCH), dim3(BS), 131072, stream,
                       ts, W0, b0, Wh, bh, Wl, bl, betaW, betab, hvec, scale,
                       y0log, out, zA64, zB64, dh64, arr, ctrl);
}